// Round 12
// baseline (148.405 us; speedup 1.0000x reference)
//
#include <hip/hip_runtime.h>

#define BIGF 1e9f
#define TT 512
#define DD 256
#define NB 64
#define DROWS 1088    // diag rows per batch (1023 used + prefetch overrun pad)

typedef float floatx16 __attribute__((ext_vector_type(16)));
typedef __bf16 bf16x8 __attribute__((ext_vector_type(8)));

// ---------- DPP wave shifts: lane i <- lane i-1 (shr) / lane i+1 (shl); invalid lanes get `oldv`
__device__ __forceinline__ float dpp_wave_shr1(float x, float oldv) {
  int r = __builtin_amdgcn_update_dpp(__builtin_bit_cast(int, oldv),
                                      __builtin_bit_cast(int, x),
                                      0x138, 0xF, 0xF, false);  // WAVE_SHR1
  return __builtin_bit_cast(float, r);
}
__device__ __forceinline__ float dpp_wave_shl1(float x, float oldv) {
  int r = __builtin_amdgcn_update_dpp(__builtin_bit_cast(int, oldv),
                                      __builtin_bit_cast(int, x),
                                      0x130, 0xF, 0xF, false);  // WAVE_SHL1
  return __builtin_bit_cast(float, r);
}

__device__ __forceinline__ bf16x8 cvt8(const float4 a, const float4 b) {
  bf16x8 v;
  v[0] = (__bf16)a.x; v[1] = (__bf16)a.y; v[2] = (__bf16)a.z; v[3] = (__bf16)a.w;
  v[4] = (__bf16)b.x; v[5] = (__bf16)b.y; v[6] = (__bf16)b.z; v[7] = (__bf16)b.w;
  return v;
}
__device__ __forceinline__ float sq4(const float4 a) {
  return a.x * a.x + a.y * a.y + a.z * a.z + a.w * a.w;
}

// ---------- Kernel B: banded cost via bf16 MFMA, NO LDS / NO BARRIERS ----------
// One 32x32 (i,j) tile per WAVE. The mfma_32x32x16 A/B fragment (lane(ln,kh) holds
// row ln, k = kh*8..kh*8+8) is loaded DIRECTLY from row-major global (2 float4 per
// lane per operand per k-step), cvt to bf16 in-register -> MFMA. Waves are fully
// independent: loads pipeline under vmcnt with no barrier coupling (the 2-barrier
// LDS k-loop was the structural stall in R8-R11: every pipe <30% busy).
// Norms: each lane accumulates sumsq of its OWN row's k-half; one shfl_xor(32)
// combines halves; epilogue fetches rA[row] by intra-wave shfl (row uniform per reg).
// Tiling: 16 i-tiles x 5 j-tiles (j0 = i0-64+32s covers band [i0-50, i0+81]) = 80
// waves/batch; block = 4 waves of one batch; b = n%64 keeps batch on XCD b%8.
// g==0 blocks also paint corner-invalid diag cells with BIG (poison 0xAA = -3e-13).
__global__ __launch_bounds__(256) void cost_kernel(const float* __restrict__ x1,
                                                   const float* __restrict__ x2,
                                                   float* __restrict__ diag) {
  const int n = blockIdx.x;
  const int b = n & 63;       // batch; XCD b%8
  const int g = n >> 6;       // tile group 0..19
  const int t = threadIdx.x;
  const int lane = t & 63;
  const int w = t >> 6;       // wave 0..3
  const int tile = g * 4 + w; // 0..79
  const int it = tile / 5;
  const int s = tile - 5 * it;
  const int i0 = it * 32;
  const int j0 = i0 - 64 + s * 32;
  const int ln = lane & 31;
  const int kh = lane >> 5;   // k-half (0/1)

  float* db = diag + (size_t)b * (DROWS * 64);

  // corner paint (64 blocks, one per batch; overlapped with all other compute)
  if (g == 0) {
    for (int r = w; r < 180; r += 4) {
      const int d = (r < 64) ? r : r + 908;  // [0,64) U [972,1088)
      const int p = d & 1;
      const int i = (d >> 1) + lane + p - 25;
      const int j = d - i;
      const int k = 2 * lane + p;
      if (k > 100 || (unsigned)i >= TT || (unsigned)j >= TT)
        db[(size_t)d * 64 + lane] = BIGF;
    }
  }

  const float* x1b = x1 + (size_t)b * (TT * DD);
  const float* x2b = x2 + (size_t)b * (TT * DD);
  const float* pA = x1b + (size_t)(i0 + ln) * DD + kh * 8;  // own A row, own k-half
  int gj = j0 + ln;
  gj = gj < 0 ? 0 : (gj > TT - 1 ? TT - 1 : gj);
  const float* pB = x2b + (size_t)gj * DD + kh * 8;         // own B row (col), clamped

  floatx16 acc = {};
  float pa = 0.f, pb = 0.f;

  for (int ko = 0; ko < DD; ko += 64) {
#pragma unroll
    for (int kk = 0; kk < 64; kk += 16) {
      const float4 a0 = *(const float4*)(pA + ko + kk);
      const float4 a1 = *(const float4*)(pA + ko + kk + 4);
      const float4 b0 = *(const float4*)(pB + ko + kk);
      const float4 b1 = *(const float4*)(pB + ko + kk + 4);
      pa += sq4(a0) + sq4(a1);
      pb += sq4(b0) + sq4(b1);
      const bf16x8 fa = cvt8(a0, a1);
      const bf16x8 fb = cvt8(b0, b1);
      acc = __builtin_amdgcn_mfma_f32_32x32x16_bf16(fa, fb, acc, 0, 0, 0);
    }
  }

  // combine k-halves: lane(ln,0)+lane(ln,1) both get full row sumsq
  pa += __shfl_xor(pa, 32, 64);
  pb += __shfl_xor(pb, 32, 64);
  const float rAown = 1.0f / fmaxf(sqrtf(pa), 1e-8f);  // rinv of row i0+ln (lanes 0..31 authoritative)
  const float rBown = 1.0f / fmaxf(sqrtf(pb), 1e-8f);  // rinv of col j0+ln (own lane's col)

  // epilogue: C layout col=lane&31 (j), row=(reg&3)+8*(reg>>2)+4*kh (i)
  const int j = j0 + ln;
#pragma unroll
  for (int reg = 0; reg < 16; ++reg) {
    const int ri = (reg & 3) + 8 * (reg >> 2) + 4 * kh;
    const int i = i0 + ri;
    const int k = i - j + 50;
    const float ra = __shfl(rAown, ri, 64);  // broadcast from lane ri (uniform index)
    if ((unsigned)j < TT && (unsigned)k <= 100) {
      const float v = 1.0f - acc[reg] * ra * rBown;
      db[(size_t)(i + j) * 64 + (k >> 1)] = v;
    }
  }
}

// ---------- Kernel C: anti-diagonal DP, one wave per batch, coalesced diag reads ----------
// Band offset k = i-j+50; lane l holds cell k = 2l+p (p = d&1).
// new[k] = c + min(prev1[k-1], prev1[k+1], prev2[k])
//   p=1 (odd d): k-1 -> same lane, k+1 -> wave_shl1;  p=0: k-1 -> wave_shr1, k+1 -> same lane.
// min(prev1,prev2) computes in parallel with the DPP shift -> serial path dpp->min->add.
// Lanes l>=51 (and l==50 on odd d) masked arithmetically off the critical chain;
// corner diagonals were BIG-painted by cost_kernel's g==0 blocks.
__global__ __launch_bounds__(64) void dtw_dp_kernel(const float* __restrict__ diag,
                                                    float* __restrict__ out) {
  const int b = blockIdx.x;
  const int l = threadIdx.x;
  const bool inv_odd = (l >= 50);   // k=2l+1 > 100
  const bool inv_even = (l >= 51);  // k=2l   > 100
  const float* base = diag + (size_t)b * (DROWS * 64);
  const float* pO = base + 64 + l;   // d = 1
  const float* pE = base + 128 + l;  // d = 2
  float cr[32];
#pragma unroll
  for (int t = 0; t < 16; ++t) {
    cr[2 * t] = *pO; pO += 128;
    cr[2 * t + 1] = *pE; pE += 128;
  }
  float prev2 = BIGF;
  const float c00 = base[25];          // cost(0,0) lives at d=0, lane 25
  float prev1 = (l == 25) ? c00 : BIGF;
  float ans = BIGF;
  for (int it = 0; it < 32; ++it) {
#pragma unroll
    for (int u = 0; u < 16; ++u) {
      // odd diagonal
      const float c1 = inv_odd ? BIGF : cr[2 * u];
      cr[2 * u] = *pO; pO += 128;  // prefetch 32 diagonals ahead (stays within DROWS pad)
      const float m12 = fminf(prev1, prev2);     // off-chain, overlaps DPP
      const float sh = dpp_wave_shl1(prev1, BIGF);
      const float m3 = fminf(sh, m12);
      prev2 = prev1;
      prev1 = c1 + m3;
      // even diagonal
      const float c2 = inv_even ? BIGF : cr[2 * u + 1];
      cr[2 * u + 1] = *pE; pE += 128;
      const float m12b = fminf(prev1, prev2);
      const float sh2 = dpp_wave_shr1(prev1, BIGF);
      const float m32 = fminf(sh2, m12b);
      prev2 = prev1;
      prev1 = c2 + m32;
      if (u == 14 && it == 31) ans = prev1;  // d = 1022 -> cell (511,511) at lane 25
    }
  }
  if (l == 25) out[b] = ans;
}

extern "C" void kernel_launch(void* const* d_in, const int* in_sizes, int n_in,
                              void* d_out, int out_size, void* d_ws, size_t ws_size,
                              hipStream_t stream) {
  const float* x1 = (const float*)d_in[0];
  const float* x2 = (const float*)d_in[1];
  float* out = (float*)d_out;
  float* diag = (float*)d_ws;  // 64*1088*64 floats = 17.8 MB

  cost_kernel<<<NB * 20, 256, 0, stream>>>(x1, x2, diag);
  dtw_dp_kernel<<<NB, 64, 0, stream>>>(diag, out);
}